// Round 15
// baseline (80.213 us; speedup 1.0000x reference)
//
#include <hip/hip_runtime.h>
#include <hip/hip_bf16.h>
#include <math.h>

// Problem constants (fixed by reference setup_inputs)
#define DH 48
#define DW 48
#define DT 48
#define DC 32
#define NPOS (DH * DW * DT)

// Position tile per block and its halo
#define TH 4
#define TW 4
#define TT 8
#define LH (TH + 2)                 // 6
#define LW (TW + 2)                 // 6
#define LT (TT + 2)                 // 10
#define NLINES (LH * LW * LT)       // 360 k-lines of 128 B
#define NF4 (NLINES * 8)            // 2880 float4 staging slots
#define NTHREADS 256                // 64 t-pairs x 4 lanes

typedef __attribute__((address_space(3))) unsigned int lds_u32_t;
typedef const __attribute__((address_space(1))) unsigned int glb_u32_t;

// quad_perm DPP add within each 4-lane quad (VALU pipe, zero LDS-pipe cost).
template <int CTRL>
__device__ __forceinline__ float qperm_add(float v) {
    const int s = __builtin_amdgcn_update_dpp(
        0, __float_as_int(v), CTRL, 0xF, 0xF, true);
    return v + __int_as_float(s);
}

// Block = 4x4x8 position tile; thread = one t-PAIR x 8 channels (4 lanes/pos).
// Each 4-line t-window serves both positions of the pair: LDS reads/pos
// drop 3.375 -> 2.25 instr, staging lines/pos 3.375 -> 2.81. Inline no-max
// softmax (invalid neighbor -> score 0 -> e=1: reference zero-pad semantics).
__global__ __launch_bounds__(NTHREADS, 3) void cotr_natt_kernel(
    const float* __restrict__ q,
    const float* __restrict__ k,
    float* __restrict__ out)
{
    __shared__ __align__(16) float kl[NLINES * DC]; // 46080 B

    // Tile origin (12 x 12 x 6 blocks)
    const int bt = blockIdx.x % (DT / TT);
    const int bw = (blockIdx.x / (DT / TT)) % (DW / TW);
    const int bh = blockIdx.x / ((DT / TT) * (DW / TW));
    const int h0 = bh * TH, w0 = bw * TW, t0 = bt * TT;

    const int tid = threadIdx.x;

    // ---- stage 360 halo lines straight into LDS (async DMA) ----
#pragma unroll
    for (int i = 0; i < 12; ++i) {
        const int s = i * NTHREADS + tid;
        if (s < NF4) {
            const int line = s >> 3, c4 = s & 7;
            const int llt = line % LT;
            const int lhw = line / LT;
            const int llw = lhw % LW;
            const int llh = lhw / LW;
            const int hh = min(max(h0 + llh - 1, 0), DH - 1);
            const int ww = min(max(w0 + llw - 1, 0), DW - 1);
            const int tt = min(max(t0 + llt - 1, 0), DT - 1);
            const float* gp =
                k + ((size_t)(hh * DW + ww) * DT + tt) * DC + c4 * 4;
            __builtin_amdgcn_global_load_lds((glb_u32_t*)gp,
                                             (lds_u32_t*)&kl[s * 4], 16, 0, 0);
        }
    }

    // thread decomposition: quad = one t-pair
    const int sub = tid & 3;          // channel octet 0..3
    const int pair = tid >> 2;        // 0..63
    const int ltp = pair & 3;         // t-pair index -> local t = 2*ltp
    const int lw = (pair >> 2) & 3;
    const int lh = pair >> 4;
    const int lt0 = ltp * 2;
    const int h = h0 + lh, w = w0 + lw, tb = t0 + lt0;  // pos0=tb, pos1=tb+1
    const int idx0 = (h * DW + w) * DT + tb;

    // q for both positions, this lane's 8 channels (overlaps the DMA)
    const float4* qp = reinterpret_cast<const float4*>(q + (size_t)idx0 * DC);
    const float4 qA0 = qp[sub * 2],     qA1 = qp[sub * 2 + 1];
    const float4 qB0 = qp[8 + sub * 2], qB1 = qp[8 + sub * 2 + 1];

    // Validity (zero-pad semantics). Line l (t = tb-1+l) validity is shared:
    // pos0 uses it as c=l, pos1 as c=l-1, same physical t.
    float as_[3], bs_[3], tv[4];
#pragma unroll
    for (int u = 0; u < 3; ++u) {
        as_[u] = ((unsigned)(h + u - 1) < DH) ? 1.0f : 0.0f;
        bs_[u] = ((unsigned)(w + u - 1) < DW) ? 1.0f : 0.0f;
    }
#pragma unroll
    for (int l = 0; l < 4; ++l)
        tv[l] = ((unsigned)(tb - 1 + l) < DT) ? 1.0f : 0.0f;

    __syncthreads();

    // ---- fused: per spatial neighbor, read 4 t-lines once, dot both
    // positions, exp, accumulate. No part[], no max pass. ----
    float s0 = 0.f, oh0 = 0.f, ow0 = 0.f, ot0 = 0.f;
    float s1 = 0.f, oh1 = 0.f, ow1 = 0.f, ot1 = 0.f;
#pragma unroll
    for (int a = 0; a < 3; ++a) {
#pragma unroll
        for (int b = 0; b < 3; ++b) {
            const float sab = as_[a] * bs_[b];
            const int lbase = ((lh + a) * LW + (lw + b)) * LT + lt0;
#pragma unroll
            for (int l = 0; l < 4; ++l) {
                const float4* kp =
                    reinterpret_cast<const float4*>(&kl[(lbase + l) * DC]);
                const float4 ka = kp[sub * 2];
                const float4 kb = kp[sub * 2 + 1];
                const float sc = sab * tv[l];
                if (l <= 2) {  // pos0, c = l
                    float d =
                        fmaf(qA0.x, ka.x, fmaf(qA0.y, ka.y,
                        fmaf(qA0.z, ka.z, fmaf(qA0.w, ka.w,
                        fmaf(qA1.x, kb.x, fmaf(qA1.y, kb.y,
                        fmaf(qA1.z, kb.z, qA1.w * kb.w)))))));
                    d = qperm_add<0xB1>(d);
                    d = qperm_add<0x4E>(d);
                    const float e = __expf(d * sc);
                    s0 += e;
                    if (a == 0) oh0 -= e;
                    if (a == 2) oh0 += e;
                    if (b == 0) ow0 -= e;
                    if (b == 2) ow0 += e;
                    if (l == 0) ot0 -= e;
                    if (l == 2) ot0 += e;
                }
                if (l >= 1) {  // pos1, c = l-1
                    float d =
                        fmaf(qB0.x, ka.x, fmaf(qB0.y, ka.y,
                        fmaf(qB0.z, ka.z, fmaf(qB0.w, ka.w,
                        fmaf(qB1.x, kb.x, fmaf(qB1.y, kb.y,
                        fmaf(qB1.z, kb.z, qB1.w * kb.w)))))));
                    d = qperm_add<0xB1>(d);
                    d = qperm_add<0x4E>(d);
                    const float e = __expf(d * sc);
                    s1 += e;
                    if (a == 0) oh1 -= e;
                    if (a == 2) oh1 += e;
                    if (b == 0) ow1 -= e;
                    if (b == 2) ow1 += e;
                    if (l == 1) ot1 -= e;
                    if (l == 3) ot1 += e;
                }
            }
        }
    }

    const float i0 = 1.0f / s0;
    const float i1 = 1.0f / s1;

    // Output [B, 3, H, W, T]; lanes 0/1/2 of each quad write dh/dw/dt for
    // both positions (t-adjacent -> contiguous addresses).
    if (sub == 0) {
        out[0 * NPOS + idx0]     = oh0 * i0;
        out[0 * NPOS + idx0 + 1] = oh1 * i1;
    } else if (sub == 1) {
        out[1 * NPOS + idx0]     = ow0 * i0;
        out[1 * NPOS + idx0 + 1] = ow1 * i1;
    } else if (sub == 2) {
        out[2 * NPOS + idx0]     = ot0 * i0;
        out[2 * NPOS + idx0 + 1] = ot1 * i1;
    }
}

extern "C" void kernel_launch(void* const* d_in, const int* in_sizes, int n_in,
                              void* d_out, int out_size, void* d_ws, size_t ws_size,
                              hipStream_t stream) {
    const float* q = reinterpret_cast<const float*>(d_in[0]);
    const float* k = reinterpret_cast<const float*>(d_in[1]);
    float* out = reinterpret_cast<float*>(d_out);

    const int blocks = (DH / TH) * (DW / TW) * (DT / TT); // 12*12*6 = 864
    cotr_natt_kernel<<<blocks, NTHREADS, 0, stream>>>(q, k, out);
}